// Round 1
// baseline (7426.913 us; speedup 1.0000x reference)
//
#include <hip/hip_runtime.h>
#include <hip/hip_cooperative_groups.h>
#include <cstdint>
#include <cstddef>
#include <cmath>

namespace cg = cooperative_groups;

#define H  2048
#define BB 2048   // batch
#define TT 64     // time steps
#define NC 10     // classes

typedef __bf16 bf16;
typedef bf16  bf16x8 __attribute__((ext_vector_type(8)));
typedef bf16  bf16x4 __attribute__((ext_vector_type(4)));
typedef float f32x4  __attribute__((ext_vector_type(4)));

// ---------------------------------------------------------------------------
// async global->LDS, 16B per lane. LDS base must be wave-uniform.
// ---------------------------------------------------------------------------
__device__ __forceinline__ void load_lds16(const void* g, void* l) {
    __builtin_amdgcn_global_load_lds(
        (__attribute__((address_space(1))) void*)(void*)g,
        (__attribute__((address_space(3))) void*)l,
        16, 0, 0);
}

// ---------------------------------------------------------------------------
// fp32 -> bf16 convert (W_hh), 4 elems/thread
// ---------------------------------------------------------------------------
__global__ void f32_to_bf16_kernel(const float* __restrict__ in,
                                   bf16* __restrict__ out, int n) {
    int i = (blockIdx.x * blockDim.x + threadIdx.x) * 4;
    if (i + 3 < n) {
        float4 v = *(const float4*)(in + i);
        bf16x4 o;
        o[0] = (bf16)v.x; o[1] = (bf16)v.y; o[2] = (bf16)v.z; o[3] = (bf16)v.w;
        *(bf16x4*)(out + i) = o;
    }
}

// ---------------------------------------------------------------------------
// Persistent RNN kernel. State S = h^T stored [B, H] bf16 (K-contiguous).
// Per step t: z[b,i] = sum_k S[b,k]*W[i,k] + Whx[i]*x[b,t] + bh[i];
//             S'[b,i] = tanh(z).  GEMM: A = S (M=B), Bt = W_hh (N=H), both
// row-major K-contiguous -> m97-style gemm_bt with 128x128 tile, BK=64.
// grid = 256 blocks (16x16 tiles), block = 256 threads (4 waves, 64x64 quad
// per wave, 4x4 frags of 16x16x32 bf16 MFMA).
// ---------------------------------------------------------------------------
__launch_bounds__(256, 1)
__global__ void rnn_persistent(const float* __restrict__ x,     // [B, T]
                               const float* __restrict__ Whx,   // [H]
                               const float* __restrict__ bh,    // [H]
                               const bf16*  __restrict__ Wb,    // [H, H] bf16
                               bf16* __restrict__ S0,           // [B, H]
                               bf16* __restrict__ S1) {         // [B, H]
    __shared__ __align__(16) bf16 As[128 * 64];  // S tile   [128 rows x 64 k]
    __shared__ __align__(16) bf16 Bs[128 * 64];  // W tile   [128 rows x 64 k]

    const int tid  = threadIdx.x;
    const int w    = tid >> 6;          // wave 0..3
    const int lane = tid & 63;
    const int bm0  = (blockIdx.x >> 4) * 128;   // batch-row tile origin
    const int bn0  = (blockIdx.x & 15) * 128;   // hidden-col tile origin
    const int qm   = (w >> 1) * 64;             // wave quadrant
    const int qn   = (w & 1) * 64;
    const int lrow = lane & 15;
    const int quad = lane >> 4;

    // staging thread mapping: row = tid/8 (+32*i), col = (tid%8)*8
    const int srow = tid >> 3;
    const int scol = (tid & 7) * 8;

    cg::grid_group grid = cg::this_grid();

    // column-invariant epilogue params (col = bn0 + qn + fn*16 + lrow)
    float wx[4], bb[4];
#pragma unroll
    for (int fn = 0; fn < 4; ++fn) {
        int col = bn0 + qn + fn * 16 + lrow;
        wx[fn] = Whx[col];
        bb[fn] = bh[col];
    }

    for (int t = 0; t < TT; ++t) {
        const bf16* Sr = (t & 1) ? S1 : S0;   // read buffer (unused at t=0)
        bf16*       Sw = (t & 1) ? S0 : S1;   // write buffer

        f32x4 acc[4][4];
#pragma unroll
        for (int i = 0; i < 4; ++i)
#pragma unroll
            for (int j = 0; j < 4; ++j) acc[i][j] = (f32x4){0.f, 0.f, 0.f, 0.f};

        if (t > 0) {
            for (int k0 = 0; k0 < H; k0 += 64) {
                __syncthreads();   // LDS free from previous iter
#pragma unroll
                for (int i = 0; i < 4; ++i) {
                    const bf16* g = Sr + (size_t)(bm0 + srow + 32 * i) * H + k0 + scol;
                    load_lds16(g, &As[(i * 256 + w * 64) * 8]);
                }
#pragma unroll
                for (int i = 0; i < 4; ++i) {
                    const bf16* g = Wb + (size_t)(bn0 + srow + 32 * i) * H + k0 + scol;
                    load_lds16(g, &Bs[(i * 256 + w * 64) * 8]);
                }
                __syncthreads();   // staging complete (vmcnt drained by barrier)

#pragma unroll
                for (int kc = 0; kc < 2; ++kc) {
                    bf16x8 af[4], bfr[4];
#pragma unroll
                    for (int f = 0; f < 4; ++f)
                        af[f] = *(const bf16x8*)&As[(qm + f * 16 + lrow) * 64 + kc * 32 + quad * 8];
#pragma unroll
                    for (int f = 0; f < 4; ++f)
                        bfr[f] = *(const bf16x8*)&Bs[(qn + f * 16 + lrow) * 64 + kc * 32 + quad * 8];
#pragma unroll
                    for (int fm = 0; fm < 4; ++fm)
#pragma unroll
                        for (int fn = 0; fn < 4; ++fn)
                            acc[fm][fn] = __builtin_amdgcn_mfma_f32_16x16x32_bf16(
                                af[fm], bfr[fn], acc[fm][fn], 0, 0, 0);
                }
            }
        }

        // epilogue: z += Whx[i]*x[b,t] + bh[i]; tanh; store bf16.
        // C layout (16x16x32): col = lane&15, row = quad*4 + reg  [m89-verified]
#pragma unroll
        for (int fm = 0; fm < 4; ++fm) {
            int rb = bm0 + qm + fm * 16 + quad * 4;
            float xv[4];
#pragma unroll
            for (int r = 0; r < 4; ++r) xv[r] = x[(rb + r) * TT + t];
#pragma unroll
            for (int fn = 0; fn < 4; ++fn) {
                int col = bn0 + qn + fn * 16 + lrow;
#pragma unroll
                for (int r = 0; r < 4; ++r) {
                    float z = acc[fm][fn][r] + wx[fn] * xv[r] + bb[fn];
                    Sw[(size_t)(rb + r) * H + col] = (bf16)tanhf(z);
                }
            }
        }

        __threadfence();   // release writes (cross-XCD L2 writeback)
        grid.sync();
        __threadfence();   // acquire (invalidate potentially-stale L2 lines)
    }
}

// ---------------------------------------------------------------------------
// out[b,c] = sum_h Why[h,c] * S[b,h] + bp[c]   (S = h_T^T, [B,H] bf16)
// one block per batch row
// ---------------------------------------------------------------------------
__global__ void out_proj(const bf16* __restrict__ S,
                         const float* __restrict__ Why,   // [H, C]
                         const float* __restrict__ bp,    // [C]
                         float* __restrict__ out) {       // [B, C]
    int b = blockIdx.x, tid = threadIdx.x;
    float p[NC];
#pragma unroll
    for (int c = 0; c < NC; ++c) p[c] = 0.f;
    for (int h = tid; h < H; h += 256) {
        float s = (float)S[(size_t)b * H + h];
        const float* wr = Why + h * NC;
#pragma unroll
        for (int c = 0; c < NC; ++c) p[c] += s * wr[c];
    }
    __shared__ float red[256 * NC];
#pragma unroll
    for (int c = 0; c < NC; ++c) red[tid * NC + c] = p[c];
    __syncthreads();
    for (int s = 128; s > 0; s >>= 1) {
        if (tid < s)
#pragma unroll
            for (int c = 0; c < NC; ++c) red[tid * NC + c] += red[(tid + s) * NC + c];
        __syncthreads();
    }
    if (tid < NC) out[(size_t)b * NC + tid] = red[tid] + bp[tid];
}

// ---------------------------------------------------------------------------
extern "C" void kernel_launch(void* const* d_in, const int* in_sizes, int n_in,
                              void* d_out, int out_size, void* d_ws, size_t ws_size,
                              hipStream_t stream) {
    const float* x   = (const float*)d_in[0];   // [B, T]
    const float* Whx = (const float*)d_in[1];   // [H, 1]
    const float* Whh = (const float*)d_in[2];   // [H, H]
    const float* Why = (const float*)d_in[3];   // [H, C]
    const float* bh  = (const float*)d_in[4];   // [H, 1]
    const float* bp  = (const float*)d_in[5];   // [C, 1]
    float* out = (float*)d_out;

    // workspace: Wb (8 MB) | S0 (8 MB) | S1 (8 MB)
    bf16* Wb = (bf16*)d_ws;
    bf16* S0 = (bf16*)((char*)d_ws + (size_t)8 * 1024 * 1024);
    bf16* S1 = (bf16*)((char*)d_ws + (size_t)16 * 1024 * 1024);

    hipLaunchKernelGGL(f32_to_bf16_kernel, dim3((H * H) / (256 * 4)), dim3(256),
                       0, stream, Whh, Wb, H * H);

    void* args[] = {(void*)&x, (void*)&Whx, (void*)&bh,
                    (void*)&Wb, (void*)&S0, (void*)&S1};
    hipLaunchCooperativeKernel((const void*)rnn_persistent, dim3(256), dim3(256),
                               args, 0, stream);

    hipLaunchKernelGGL(out_proj, dim3(BB), dim3(256), 0, stream, S0, Why, bp, out);
}

// Round 4
// 2040.342 us; speedup vs baseline: 3.6400x; 3.6400x over previous
//
#include <hip/hip_runtime.h>
#include <cstdint>
#include <cstddef>
#include <cmath>

#define H  2048
#define BB 2048   // batch
#define TT 64     // time steps
#define NC 10     // classes
#define BK 64     // K-chunk per staging iter (8 x 16B chunks per row)

typedef __bf16 bf16;
typedef bf16  bf16x8 __attribute__((ext_vector_type(8)));
typedef bf16  bf16x4 __attribute__((ext_vector_type(4)));
typedef float f32x4  __attribute__((ext_vector_type(4)));

// ---------------------------------------------------------------------------
// async global->LDS, 16B per lane. LDS dest is wave-uniform base + lane*16.
// ---------------------------------------------------------------------------
__device__ __forceinline__ void load_lds16(const void* g, void* l) {
    __builtin_amdgcn_global_load_lds(
        (__attribute__((address_space(1))) void*)(void*)g,
        (__attribute__((address_space(3))) void*)l,
        16, 0, 0);
}

// ---------------------------------------------------------------------------
// fp32 -> bf16 convert (W_hh), 4 elems/thread
// ---------------------------------------------------------------------------
__global__ void f32_to_bf16_kernel(const float* __restrict__ in,
                                   bf16* __restrict__ out, int n) {
    int i = (blockIdx.x * blockDim.x + threadIdx.x) * 4;
    if (i + 3 < n) {
        float4 v = *(const float4*)(in + i);
        bf16x4 o;
        o[0] = (bf16)v.x; o[1] = (bf16)v.y; o[2] = (bf16)v.z; o[3] = (bf16)v.w;
        *(bf16x4*)(out + i) = o;
    }
}

// ---------------------------------------------------------------------------
// t = 0: S[b,i] = tanh(Whx[i]*x[b,0] + bh[i]).  One block per batch row.
// ---------------------------------------------------------------------------
__global__ void rnn_init(const float* __restrict__ x,     // [B, T]
                         const float* __restrict__ Whx,   // [H]
                         const float* __restrict__ bh,    // [H]
                         bf16* __restrict__ S) {          // [B, H]
    int b  = blockIdx.x;
    int i0 = threadIdx.x * 8;
    float xv = x[(size_t)b * TT];
    bf16x8 o;
#pragma unroll
    for (int j = 0; j < 8; ++j)
        o[j] = (bf16)tanhf(Whx[i0 + j] * xv + bh[i0 + j]);
    *(bf16x8*)(S + (size_t)b * H + i0) = o;
}

// ---------------------------------------------------------------------------
// One RNN time step (plain launch, no cooperative groups):
//   Sw[b,i] = tanh( sum_k Sr[b,k]*Wb[i,k] + Whx[i]*x[b,t] + bh[i] )
//
// 128(m) x 64(n) tile per block, BK=64, grid 512 -> 2 blocks/CU so one
// block's barrier-drain overlaps the other's MFMA (m114). 24 KB static LDS.
//
// LDS XOR swizzle (kills Round-1's 16-way ds_read_b128 conflicts, 3.96e8
// conflict cycles): 16B chunk l of tile row r holds global chunk l^(r&7).
// global_load_lds forces dest = base + lane*16, so the swizzle is applied by
// permuting the global SOURCE chunk per lane (XOR is involutive).
// Frag read: lanes of one quad hit all 8 chunk-groups -> 2 lanes/bank = free.
// ---------------------------------------------------------------------------
__launch_bounds__(256)
__global__ void rnn_step(const float* __restrict__ x,     // [B, T]
                         const float* __restrict__ Whx,   // [H]
                         const float* __restrict__ bh,    // [H]
                         const bf16*  __restrict__ Wb,    // [H, H] bf16
                         const bf16*  __restrict__ Sr,    // [B, H] read
                         bf16* __restrict__ Sw,           // [B, H] write
                         int t) {
    __shared__ __align__(16) bf16 As[128 * BK];  // 16 KB (S tile, m-rows)
    __shared__ __align__(16) bf16 Bs[64 * BK];   //  8 KB (W tile, n-rows)

    const int tid  = threadIdx.x;
    const int w    = tid >> 6;          // wave 0..3
    const int lane = tid & 63;

    // XCD-aware mapping: blockIdx round-robins over 8 XCDs; 4 bn-tiles/XCD
    // -> each XCD's 1 MB W-slice stays L2-resident.
    const int xcd = blockIdx.x & 7;
    const int loc = blockIdx.x >> 3;             // 0..63
    const int bn0 = (xcd * 4 + (loc & 3)) * 64;  // hidden-col tile origin
    const int bm0 = (loc >> 2) * 128;            // batch-row tile origin

    const int qm   = (w & 1) * 64;               // wave m-quadrant (64 rows)
    const int qn   = (w >> 1) * 32;              // wave n-quadrant (32 cols)
    const int lrow = lane & 15;
    const int quad = lane >> 4;

    const int s_r = tid >> 3;                    // staging row within 32-group
    const int s_l = tid & 7;                     // staging LDS chunk in row

    f32x4 acc[4][2];
#pragma unroll
    for (int i = 0; i < 4; ++i)
#pragma unroll
        for (int j = 0; j < 2; ++j) acc[i][j] = (f32x4){0.f, 0.f, 0.f, 0.f};

    for (int k0 = 0; k0 < H; k0 += BK) {
        if (k0) __syncthreads();   // previous iter's LDS reads done
        // A tile: 128 rows x 8 chunks = 1024 chunks; 4 wave-instrs
#pragma unroll
        for (int i = 0; i < 4; ++i) {
            int r = i * 32 + s_r;                 // tile row 0..127
            int g = s_l ^ (r & 7);                // swizzled source chunk
            load_lds16(Sr + (size_t)(bm0 + r) * H + k0 + g * 8,
                       &As[(i * 256 + w * 64) * 8]);
        }
        // B tile: 64 rows x 8 chunks; 2 wave-instrs
#pragma unroll
        for (int i = 0; i < 2; ++i) {
            int r = i * 32 + s_r;                 // tile row 0..63
            int g = s_l ^ (r & 7);
            load_lds16(Wb + (size_t)(bn0 + r) * H + k0 + g * 8,
                       &Bs[(i * 256 + w * 64) * 8]);
        }
        __syncthreads();   // staging complete (barrier drains vmcnt)

#pragma unroll
        for (int kc = 0; kc < 2; ++kc) {
            bf16x8 af[4], bfr[2];
#pragma unroll
            for (int f = 0; f < 4; ++f) {
                int row = qm + f * 16 + lrow;
                int g   = kc * 4 + quad;
                int l   = g ^ (row & 7);
                af[f] = *(const bf16x8*)&As[(row * 8 + l) * 8];
            }
#pragma unroll
            for (int f = 0; f < 2; ++f) {
                int row = qn + f * 16 + lrow;
                int g   = kc * 4 + quad;
                int l   = g ^ (row & 7);
                bfr[f] = *(const bf16x8*)&Bs[(row * 8 + l) * 8];
            }
#pragma unroll
            for (int fm = 0; fm < 4; ++fm)
#pragma unroll
                for (int fn = 0; fn < 2; ++fn)
                    acc[fm][fn] = __builtin_amdgcn_mfma_f32_16x16x32_bf16(
                        af[fm], bfr[fn], acc[fm][fn], 0, 0, 0);
        }
    }

    // epilogue: z += Whx[i]*x[b,t] + bh[i]; tanh; store bf16.
    // C layout (16x16x32): col = lane&15, row = quad*4 + reg  [m89-verified]
#pragma unroll
    for (int fm = 0; fm < 4; ++fm) {
        int rb = bm0 + qm + fm * 16 + quad * 4;
        float xv[4];
#pragma unroll
        for (int r = 0; r < 4; ++r) xv[r] = x[(size_t)(rb + r) * TT + t];
#pragma unroll
        for (int fn = 0; fn < 2; ++fn) {
            int col = bn0 + qn + fn * 16 + lrow;
            float wx = Whx[col], bb = bh[col];
#pragma unroll
            for (int r = 0; r < 4; ++r) {
                float z = acc[fm][fn][r] + wx * xv[r] + bb;
                Sw[(size_t)(rb + r) * H + col] = (bf16)tanhf(z);
            }
        }
    }
}

// ---------------------------------------------------------------------------
// out[b,c] = sum_h Why[h,c] * S[b,h] + bp[c]   (S = h_T^T, [B,H] bf16)
// one block per batch row
// ---------------------------------------------------------------------------
__global__ void out_proj(const bf16* __restrict__ S,
                         const float* __restrict__ Why,   // [H, C]
                         const float* __restrict__ bp,    // [C]
                         float* __restrict__ out) {       // [B, C]
    int b = blockIdx.x, tid = threadIdx.x;
    float p[NC];
#pragma unroll
    for (int c = 0; c < NC; ++c) p[c] = 0.f;
    for (int h = tid; h < H; h += 256) {
        float s = (float)S[(size_t)b * H + h];
        const float* wr = Why + h * NC;
#pragma unroll
        for (int c = 0; c < NC; ++c) p[c] += s * wr[c];
    }
    __shared__ float red[256 * NC];
#pragma unroll
    for (int c = 0; c < NC; ++c) red[tid * NC + c] = p[c];
    __syncthreads();
    for (int s = 128; s > 0; s >>= 1) {
        if (tid < s)
#pragma unroll
            for (int c = 0; c < NC; ++c) red[tid * NC + c] += red[(tid + s) * NC + c];
        __syncthreads();
    }
    if (tid < NC) out[(size_t)b * NC + tid] = red[tid] + bp[tid];
}

// ---------------------------------------------------------------------------
extern "C" void kernel_launch(void* const* d_in, const int* in_sizes, int n_in,
                              void* d_out, int out_size, void* d_ws, size_t ws_size,
                              hipStream_t stream) {
    const float* x   = (const float*)d_in[0];   // [B, T]
    const float* Whx = (const float*)d_in[1];   // [H, 1]
    const float* Whh = (const float*)d_in[2];   // [H, H]
    const float* Why = (const float*)d_in[3];   // [H, C]
    const float* bh  = (const float*)d_in[4];   // [H, 1]
    const float* bp  = (const float*)d_in[5];   // [C, 1]
    float* out = (float*)d_out;

    // workspace: Wb (8 MB) | S0 (8 MB) | S1 (8 MB)
    bf16* Wb = (bf16*)d_ws;
    bf16* S0 = (bf16*)((char*)d_ws + (size_t)8 * 1024 * 1024);
    bf16* S1 = (bf16*)((char*)d_ws + (size_t)16 * 1024 * 1024);

    hipLaunchKernelGGL(f32_to_bf16_kernel, dim3((H * H) / (256 * 4)), dim3(256),
                       0, stream, Whh, Wb, H * H);

    // t = 0 writes S1; step t reads (t&1 ? S1 : S0), writes the other.
    hipLaunchKernelGGL(rnn_init, dim3(BB), dim3(256), 0, stream, x, Whx, bh, S1);

    for (int t = 1; t < TT; ++t) {
        const bf16* Srd = (t & 1) ? S1 : S0;
        bf16*       Swr = (t & 1) ? S0 : S1;
        hipLaunchKernelGGL(rnn_step, dim3(512), dim3(256), 0, stream,
                           x, Whx, bh, Wb, Srd, Swr, t);
    }

    // t=63 (odd) wrote S0
    hipLaunchKernelGGL(out_proj, dim3(BB), dim3(256), 0, stream, S0, Why, bp, out);
}